// Round 1
// baseline (302.548 us; speedup 1.0000x reference)
//
#include <hip/hip_runtime.h>
#include <hip/hip_bf16.h>
#include <cstdint>
#include <cstddef>

typedef __bf16 bf16_t;
typedef __bf16 bf16x4 __attribute__((ext_vector_type(4)));
typedef __bf16 bf16x8 __attribute__((ext_vector_type(8)));
typedef float  f32x4  __attribute__((ext_vector_type(4)));

#define NB   16
#define NC   256
#define NO   256
#define SD   512
#define NPIX 4096   // 64*64
#define CPAD 36     // LDS channel pad: breaks pow2 banks, keeps 8B alignment

// workspace layout (bytes)
#define WS_S   0        // s   [16][256] f32  (16 KB)
#define WS_D   16384    // d   [16][256] f32  (16 KB)
#define WS_WSQ 32768    // wsq [256][256] f32 (256 KB)
#define WS_WT  294912   // wT  [9][256][256] bf16 (1.125 MB)

// ---------------------------------------------------------------------------
// prep1: blocks 0..15  -> s[b,i]   = style[b,:] . mod_w[i,:] + mod_b[i]
//        blocks 16..271-> wsq[o,i] = sum_t w[o,i,t]^2 ; wT[t][o][i] = bf16(w[o][i][t])
// ---------------------------------------------------------------------------
__global__ __launch_bounds__(256) void prep1(
    const float* __restrict__ style, const float* __restrict__ weight,
    const float* __restrict__ mod_w, const float* __restrict__ mod_b,
    float* __restrict__ s_buf, float* __restrict__ wsq, bf16_t* __restrict__ wT)
{
    const int blk = blockIdx.x;
    const int tid = threadIdx.x;
    if (blk < 16) {
        const int b = blk, i = tid;
        const float* st = style + b * SD;
        const float* mw = mod_w + i * SD;
        float acc = 0.f;
        for (int k = 0; k < SD; k += 4) {
            float4 a = *(const float4*)(st + k);
            float4 c = *(const float4*)(mw + k);
            acc += a.x * c.x + a.y * c.y + a.z * c.z + a.w * c.w;
        }
        s_buf[b * NC + i] = acc + mod_b[i];
    } else {
        const int o = blk - 16, i = tid;
        const float* wp = weight + (o * NC + i) * 9;
        float q = 0.f;
        #pragma unroll
        for (int t = 0; t < 9; ++t) {
            float v = wp[t];
            q += v * v;
            wT[t * (NO * NC) + o * NC + i] = (bf16_t)v;
        }
        wsq[o * NC + i] = q;
    }
}

// ---------------------------------------------------------------------------
// prep2: d[b,o] = rsqrt( sum_i wsq[o,i] * s[b,i]^2 + eps )
// ---------------------------------------------------------------------------
__global__ __launch_bounds__(256) void prep2(
    const float* __restrict__ s_buf, const float* __restrict__ wsq,
    float* __restrict__ d_buf)
{
    const int b = blockIdx.x, o = threadIdx.x;
    const float* wq = wsq + o * NC;
    const float* sb = s_buf + b * NC;
    float sum = 0.f;
    for (int i = 0; i < NC; ++i) {
        float sv = sb[i];
        sum += wq[i] * sv * sv;
    }
    d_buf[b * NC + o] = rsqrtf(sum + 1e-8f);
}

// ---------------------------------------------------------------------------
// conv: implicit-GEMM, per batch:  C[o,p] = sum_{tap,ic} wT[tap][o][ic] * xs[...]
// Block: 128 out_ch x 128 positions (2 image rows); 4 waves, each 64x64 via
// 4x4 frags of mfma_f32_16x16x32_bf16.
// A (weights, bf16, 1.18 MB total -> L2-resident) loaded DIRECTLY to VGPRs,
// prefetched one tap ahead -> no A-LDS, no per-tap barriers.
// B (x*s) double-buffered in LDS: stage chunk k+1 while computing chunk k's
// 9 taps; ONE barrier per chunk (9 total vs ~80 before).
// ---------------------------------------------------------------------------
__global__ __launch_bounds__(256, 3) void conv_mfma(
    const float* __restrict__ x,
    const bf16_t* __restrict__ wT,
    const float* __restrict__ s_buf,
    const float* __restrict__ d_buf,
    float* __restrict__ out)
{
    __shared__ bf16_t lds_b[2][4 * 64 * CPAD];   // 2 x 18 KB, B double buffer

    const int tid   = threadIdx.x;
    const int lane  = tid & 63;
    const int wv    = tid >> 6;
    const int wo    = wv >> 1;       // wave o-half
    const int wp    = wv & 1;        // wave p-half (= image row within tile)
    const int pt    = blockIdx.x;    // 0..31 position tiles (2 rows each)
    const int o0    = blockIdx.y * 128;
    const int batch = blockIdx.z;
    const int row0  = pt * 2;

    const int l15 = lane & 15;
    const int k0  = (lane >> 4) * 8;

    const int colB = tid & 63;       // staging: column
    const int cgrp = tid >> 6;       // staging: channel group (8 ch each)

    f32x4 acc[4][4];
    #pragma unroll
    for (int i = 0; i < 4; ++i)
        #pragma unroll
        for (int j = 0; j < 4; ++j) {
            f32x4 z = {0.f, 0.f, 0.f, 0.f};
            acc[i][j] = z;
        }

    bf16x8 bzero;
    #pragma unroll
    for (int j = 0; j < 8; ++j) bzero[j] = (bf16_t)0.f;

    // B staging: global x (fp32) -> regs (all 32 loads issued as one batch)
    // -> scale by s -> bf16 pack -> LDS (channel-innermost, CPAD stride)
    auto STAGE = [&](int ic0, bf16_t* __restrict__ dst) {
        const float* sp = s_buf + batch * NC + ic0 + cgrp * 8;
        float4 sa = *(const float4*)sp;
        float4 sb = *(const float4*)(sp + 4);
        float sv[8] = {sa.x, sa.y, sa.z, sa.w, sb.x, sb.y, sb.z, sb.w};
        const float* xbase = x + (size_t)(batch * NC + ic0 + cgrp * 8) * NPIX + colB;
        float v[4][8];
        #pragma unroll
        for (int r = 0; r < 4; ++r) {
            const int gy = row0 - 1 + r;
            const bool valid = ((unsigned)gy < 64u);   // block-uniform
            const float* rp = xbase + gy * 64;
            #pragma unroll
            for (int j = 0; j < 8; ++j)
                v[r][j] = valid ? rp[j * NPIX] : 0.f;
        }
        #pragma unroll
        for (int r = 0; r < 4; ++r) {
            const int lbase = (r * 64 + colB) * CPAD + cgrp * 8;
            #pragma unroll
            for (int half = 0; half < 2; ++half) {
                union { bf16_t h[4]; uint2 u; } pk;
                #pragma unroll
                for (int j = 0; j < 4; ++j)
                    pk.h[j] = (bf16_t)(v[r][half * 4 + j] * sv[half * 4 + j]);
                *(uint2*)&dst[lbase + half * 4] = pk.u;   // 8B aligned
            }
        }
    };

    const size_t TSTR = (size_t)NO * NC;  // 65536 elements per tap plane
    // per-lane A row base: o-row (o0 + wo*64 + l15), k-slice k0
    const bf16_t* aBase = wT + (size_t)(o0 + wo * 64 + l15) * NC + k0;

    // prologue: preload A frags for (chunk 0, tap 0); stage B chunk 0
    bf16x8 af[4];
    #pragma unroll
    for (int of = 0; of < 4; ++of)
        af[of] = *(const bf16x8*)(aBase + of * 16 * NC);
    STAGE(0, &lds_b[0][0]);
    __syncthreads();

    for (int chunk = 0; chunk < 8; ++chunk) {
        const int ic0 = chunk * 32;
        if (chunk < 7)
            STAGE(ic0 + 32, &lds_b[(chunk + 1) & 1][0]);   // into other buffer

        const bf16_t* bbuf = &lds_b[chunk & 1][0];
        const bf16_t* aChunk = aBase + ic0;
        const bf16_t* aNextChunk = aBase + (chunk < 7 ? ic0 + 32 : ic0); // tap 0

        #pragma unroll 1
        for (int tap = 0; tap < 9; ++tap) {
            const int kh = tap / 3;
            const int kw = tap - kh * 3;

            // prefetch next tap's A frags (or next chunk's tap 0)
            const bf16_t* aN = (tap < 8) ? (aChunk + (size_t)(tap + 1) * TSTR)
                                         : aNextChunk;
            bf16x8 afn[4];
            #pragma unroll
            for (int of = 0; of < 4; ++of)
                afn[of] = *(const bf16x8*)(aN + of * 16 * NC);

            const int r = wp + kh;   // lds row for this wave's output row + tap dy
            bf16x8 bfr[4];
            #pragma unroll
            for (int nf = 0; nf < 4; ++nf) {
                const int c = nf * 16 + l15 + kw - 1;
                if ((unsigned)c < 64u) {
                    const bf16_t* p = &bbuf[(r * 64 + c) * CPAD + k0];
                    bf16x4 lo = *(const bf16x4*)p;        // 8B aligned
                    bf16x4 hi = *(const bf16x4*)(p + 4);
                    bfr[nf] = __builtin_shufflevector(lo, hi, 0, 1, 2, 3, 4, 5, 6, 7);
                } else {
                    bfr[nf] = bzero;                       // horizontal zero-pad
                }
            }

            #pragma unroll
            for (int of = 0; of < 4; ++of)
                #pragma unroll
                for (int nf = 0; nf < 4; ++nf)
                    acc[of][nf] = __builtin_amdgcn_mfma_f32_16x16x32_bf16(
                        af[of], bfr[nf], acc[of][nf], 0, 0, 0);

            #pragma unroll
            for (int of = 0; of < 4; ++of) af[of] = afn[of];
        }
        __syncthreads();   // buf[(chunk+1)&1] fully written; buf[chunk&1] free
    }

    // ---- epilogue: y = acc * d[b,o], store fp32 ----
    const int p_base = pt * 128 + wp * 64;
    #pragma unroll
    for (int of = 0; of < 4; ++of) {
        #pragma unroll
        for (int rg = 0; rg < 4; ++rg) {
            const int o_g = o0 + wo * 64 + of * 16 + (lane >> 4) * 4 + rg;
            const float dv = d_buf[batch * NO + o_g];
            const size_t obase = (size_t)(batch * NO + o_g) * NPIX;
            #pragma unroll
            for (int nf = 0; nf < 4; ++nf) {
                const int p_g = p_base + nf * 16 + l15;
                out[obase + p_g] = acc[of][nf][rg] * dv;
            }
        }
    }
}

// ---------------------------------------------------------------------------
extern "C" void kernel_launch(void* const* d_in, const int* in_sizes, int n_in,
                              void* d_out, int out_size, void* d_ws, size_t ws_size,
                              hipStream_t stream)
{
    const float* x      = (const float*)d_in[0];
    const float* style  = (const float*)d_in[1];
    const float* weight = (const float*)d_in[2];
    const float* mod_w  = (const float*)d_in[3];
    const float* mod_b  = (const float*)d_in[4];
    float* out = (float*)d_out;

    char* ws = (char*)d_ws;
    float*  s_buf = (float*)(ws + WS_S);
    float*  d_buf = (float*)(ws + WS_D);
    float*  wsq   = (float*)(ws + WS_WSQ);
    bf16_t* wT    = (bf16_t*)(ws + WS_WT);

    hipLaunchKernelGGL(prep1, dim3(272), dim3(256), 0, stream,
                       style, weight, mod_w, mod_b, s_buf, wsq, wT);
    hipLaunchKernelGGL(prep2, dim3(16), dim3(256), 0, stream, s_buf, wsq, d_buf);
    hipLaunchKernelGGL(conv_mfma, dim3(32, 2, 16), dim3(256), 0, stream,
                       x, wT, s_buf, d_buf, out);
}

// Round 2
// 278.191 us; speedup vs baseline: 1.0876x; 1.0876x over previous
//
#include <hip/hip_runtime.h>
#include <hip/hip_bf16.h>
#include <cstdint>
#include <cstddef>

typedef __bf16 bf16_t;
typedef __bf16 bf16x4 __attribute__((ext_vector_type(4)));
typedef __bf16 bf16x8 __attribute__((ext_vector_type(8)));
typedef float  f32x4  __attribute__((ext_vector_type(4)));

#define NB   16
#define NC   256
#define NO   256
#define SD   512
#define NPIX 4096   // 64*64
#define CPAD 40     // B LDS stride (elems): 80B row stride -> 8 distinct banks,
                    // 16B-aligned so bfr is a single ds_read_b128

// workspace layout (bytes)
#define WS_S   0        // s   [16][256] f32  (16 KB)
#define WS_D   16384    // d   [16][256] f32  (16 KB)
#define WS_WSQ 32768    // wsq [256][256] f32 (256 KB)
#define WS_WT  294912   // wT  [9][256][256] bf16 (1.125 MB)

// ---------------------------------------------------------------------------
// prep1: blocks 0..15  -> s[b,i]   = style[b,:] . mod_w[i,:] + mod_b[i]
//        blocks 16..271-> wsq[o,i] = sum_t w[o,i,t]^2 ; wT[t][o][i] = bf16(w[o][i][t])
// ---------------------------------------------------------------------------
__global__ __launch_bounds__(256) void prep1(
    const float* __restrict__ style, const float* __restrict__ weight,
    const float* __restrict__ mod_w, const float* __restrict__ mod_b,
    float* __restrict__ s_buf, float* __restrict__ wsq, bf16_t* __restrict__ wT)
{
    const int blk = blockIdx.x;
    const int tid = threadIdx.x;
    if (blk < 16) {
        const int b = blk, i = tid;
        const float* st = style + b * SD;
        const float* mw = mod_w + i * SD;
        float acc = 0.f;
        for (int k = 0; k < SD; k += 4) {
            float4 a = *(const float4*)(st + k);
            float4 c = *(const float4*)(mw + k);
            acc += a.x * c.x + a.y * c.y + a.z * c.z + a.w * c.w;
        }
        s_buf[b * NC + i] = acc + mod_b[i];
    } else {
        const int o = blk - 16, i = tid;
        const float* wp = weight + (o * NC + i) * 9;
        float q = 0.f;
        #pragma unroll
        for (int t = 0; t < 9; ++t) {
            float v = wp[t];
            q += v * v;
            wT[t * (NO * NC) + o * NC + i] = (bf16_t)v;
        }
        wsq[o * NC + i] = q;
    }
}

// ---------------------------------------------------------------------------
// prep2: d[b,o] = rsqrt( sum_i wsq[o,i] * s[b,i]^2 + eps )
// ---------------------------------------------------------------------------
__global__ __launch_bounds__(256) void prep2(
    const float* __restrict__ s_buf, const float* __restrict__ wsq,
    float* __restrict__ d_buf)
{
    const int b = blockIdx.x, o = threadIdx.x;
    const float* wq = wsq + o * NC;
    const float* sb = s_buf + b * NC;
    float sum = 0.f;
    for (int i = 0; i < NC; ++i) {
        float sv = sb[i];
        sum += wq[i] * sv * sv;
    }
    d_buf[b * NC + o] = rsqrtf(sum + 1e-8f);
}

// ---------------------------------------------------------------------------
// conv: implicit-GEMM, per batch:  C[o,p] = sum_{tap,ic} wT[tap][o][ic] * xs[...]
// Block: 128 out_ch x 128 positions (2 image rows); 4 waves, each 64x64 via
// 4x4 frags of mfma_f32_16x16x32_bf16. K-loop: 8 channel chunks x 9 taps.
//
// A (weights, bf16): global_load_lds width=16, double-buffered per tap.
//   LDS layout is KGRP-MAJOR [4 kgrp][128 row][8 ch]: lane l15 reads
//   consecutive 16B segments -> conflict-free ds_read_b128 (round-0's
//   [row][32ch] layout was an 8-way conflict: 5.77M conflict-cycles).
// B (x*s): staged fp32->bf16 through VGPRs in 2-row batches (VGPR diet),
//   CPAD=40 -> single aligned ds_read_b128 per B fragment.
// ---------------------------------------------------------------------------
__device__ __forceinline__ void stage_a(const bf16_t* __restrict__ wT_tap,
                                        int o0, int ic0, bf16_t* dst, int tid)
{
    #pragma unroll
    for (int it = 0; it < 2; ++it) {
        int s = it * 256 + tid;                 // 512 16B segments
        // LDS dest linear: segment s -> (kgrp = s>>7, row = s&127)
        const bf16_t* g = wT_tap + (o0 + (s & 127)) * NC + ic0 + (s >> 7) * 8;
        __builtin_amdgcn_global_load_lds(
            (const __attribute__((address_space(1))) void*)g,
            (__attribute__((address_space(3))) void*)(dst + s * 8),
            16, 0, 0);
    }
}

__global__ __launch_bounds__(256, 3) void conv_mfma(
    const float* __restrict__ x,
    const bf16_t* __restrict__ wT,
    const float* __restrict__ s_buf,
    const float* __restrict__ d_buf,
    float* __restrict__ out)
{
    __shared__ bf16_t lds_a[2][4096];           // 2 x 8 KB, A dbuf, kgrp-major
    __shared__ bf16_t lds_b[4 * 64 * CPAD];     // 20 KB, x rows (scaled bf16)

    const int tid   = threadIdx.x;
    const int lane  = tid & 63;
    const int wv    = tid >> 6;
    const int wo    = wv >> 1;       // wave o-half
    const int wp    = wv & 1;        // wave p-half (= image row within tile)
    const int pt    = blockIdx.x;    // 0..31 position tiles (2 rows each)
    const int o0    = blockIdx.y * 128;
    const int batch = blockIdx.z;
    const int row0  = pt * 2;

    const int l15 = lane & 15;
    const int kg  = lane >> 4;       // k-group 0..3 (8 ch each)
    const int k0  = kg * 8;

    const int colB = tid & 63;       // staging: column
    const int cgrp = tid >> 6;       // staging: channel group (8 ch each)

    f32x4 acc[4][4];
    #pragma unroll
    for (int i = 0; i < 4; ++i)
        #pragma unroll
        for (int j = 0; j < 4; ++j) {
            f32x4 z = {0.f, 0.f, 0.f, 0.f};
            acc[i][j] = z;
        }

    bf16x8 bzero;
    #pragma unroll
    for (int j = 0; j < 8; ++j) bzero[j] = (bf16_t)0.f;

    // B staging: global x (fp32) -> regs -> scale -> bf16 -> LDS.
    // 2-row batches keep only 16 load regs live (VGPR diet for occupancy).
    auto STAGE = [&](int ic0) {
        const float* sp = s_buf + batch * NC + ic0 + cgrp * 8;
        float4 sa = *(const float4*)sp;
        float4 sb = *(const float4*)(sp + 4);
        float sv[8] = {sa.x, sa.y, sa.z, sa.w, sb.x, sb.y, sb.z, sb.w};
        const float* xbase = x + (size_t)(batch * NC + ic0 + cgrp * 8) * NPIX + colB;
        #pragma unroll
        for (int rh = 0; rh < 2; ++rh) {
            float v[2][8];
            #pragma unroll
            for (int rr = 0; rr < 2; ++rr) {
                const int r = rh * 2 + rr;
                const int gy = row0 - 1 + r;
                const bool valid = ((unsigned)gy < 64u);   // block-uniform
                const float* rp = xbase + gy * 64;
                #pragma unroll
                for (int j = 0; j < 8; ++j)
                    v[rr][j] = valid ? rp[j * NPIX] : 0.f;
            }
            #pragma unroll
            for (int rr = 0; rr < 2; ++rr) {
                const int r = rh * 2 + rr;
                union { bf16_t h[8]; uint4 u; } pk;
                #pragma unroll
                for (int j = 0; j < 8; ++j)
                    pk.h[j] = (bf16_t)(v[rr][j] * sv[j]);
                // byte offset = (r*64+colB)*80 + cgrp*16 -> 16B aligned b128 write
                *(uint4*)&lds_b[(r * 64 + colB) * CPAD + cgrp * 8] = pk.u;
            }
        }
    };

    const size_t TSTR = (size_t)NO * NC;  // 65536 elements per tap plane

    for (int chunk = 0; chunk < 8; ++chunk) {
        const int ic0 = chunk * 32;

        STAGE(ic0);
        stage_a(wT, o0, ic0, &lds_a[0][0], tid);   // tap 0 into buf 0
        __syncthreads();

        #pragma unroll
        for (int tap = 0; tap < 9; ++tap) {
            if (tap < 8)
                stage_a(wT + (size_t)(tap + 1) * TSTR, o0, ic0,
                        &lds_a[(tap + 1) & 1][0], tid);

            const bf16_t* abuf = &lds_a[tap & 1][0];
            const int kh = tap / 3, kw = tap % 3;

            // A frags: kgrp-major -> lanes read consecutive 16B, conflict-free
            bf16x8 af[4];
            #pragma unroll
            for (int of = 0; of < 4; ++of)
                af[of] = *(const bf16x8*)&abuf[kg * 1024 + (wo * 64 + of * 16 + l15) * 8];

            const int r = wp + kh;   // lds row for this wave's output row + tap dy
            bf16x8 bfr[4];
            #pragma unroll
            for (int nf = 0; nf < 4; ++nf) {
                const int c = nf * 16 + l15 + kw - 1;
                if ((unsigned)c < 64u) {
                    // byte = (r*64+c)*80 + k0*2 -> 16B aligned single b128
                    bfr[nf] = *(const bf16x8*)&lds_b[(r * 64 + c) * CPAD + k0];
                } else {
                    bfr[nf] = bzero;                       // horizontal zero-pad
                }
            }

            #pragma unroll
            for (int of = 0; of < 4; ++of)
                #pragma unroll
                for (int nf = 0; nf < 4; ++nf)
                    acc[of][nf] = __builtin_amdgcn_mfma_f32_16x16x32_bf16(
                        af[of], bfr[nf], acc[of][nf], 0, 0, 0);

            __syncthreads();
        }
    }

    // ---- epilogue: y = acc * d[b,o], store fp32 ----
    const int p_base = pt * 128 + wp * 64;
    #pragma unroll
    for (int of = 0; of < 4; ++of) {
        #pragma unroll
        for (int rg = 0; rg < 4; ++rg) {
            const int o_g = o0 + wo * 64 + of * 16 + (lane >> 4) * 4 + rg;
            const float dv = d_buf[batch * NO + o_g];
            const size_t obase = (size_t)(batch * NO + o_g) * NPIX;
            #pragma unroll
            for (int nf = 0; nf < 4; ++nf) {
                const int p_g = p_base + nf * 16 + l15;
                out[obase + p_g] = acc[of][nf][rg] * dv;
            }
        }
    }
}

// ---------------------------------------------------------------------------
extern "C" void kernel_launch(void* const* d_in, const int* in_sizes, int n_in,
                              void* d_out, int out_size, void* d_ws, size_t ws_size,
                              hipStream_t stream)
{
    const float* x      = (const float*)d_in[0];
    const float* style  = (const float*)d_in[1];
    const float* weight = (const float*)d_in[2];
    const float* mod_w  = (const float*)d_in[3];
    const float* mod_b  = (const float*)d_in[4];
    float* out = (float*)d_out;

    char* ws = (char*)d_ws;
    float*  s_buf = (float*)(ws + WS_S);
    float*  d_buf = (float*)(ws + WS_D);
    float*  wsq   = (float*)(ws + WS_WSQ);
    bf16_t* wT    = (bf16_t*)(ws + WS_WT);

    hipLaunchKernelGGL(prep1, dim3(272), dim3(256), 0, stream,
                       style, weight, mod_w, mod_b, s_buf, wsq, wT);
    hipLaunchKernelGGL(prep2, dim3(16), dim3(256), 0, stream, s_buf, wsq, d_buf);
    hipLaunchKernelGGL(conv_mfma, dim3(32, 2, 16), dim3(256), 0, stream,
                       x, wT, s_buf, d_buf, out);
}